// Round 4
// baseline (190.480 us; speedup 1.0000x reference)
//
#include <hip/hip_runtime.h>
#include <math.h>

#define DDIM 4096
#define EDIM 64
#define NROWS 16384
#define MBLK 32
#define NKT 32            // K-tiles of 128
#define TOPK_K 8
#define DIGIT_BIAS 0x00808080

typedef int i32x4 __attribute__((ext_vector_type(4)));

// signed-digit int8 decomposition of v: bytes of (v+BIAS)^BIAS are signed
// digits d_p with v = sum d_p * 256^p   (exact for |v| < 2^31 - 2^23)
__device__ __forceinline__ int digits_of(float f) {
  int v = __float2int_rn(f);
  return (v + DIGIT_BIAS) ^ DIGIT_BIAS;
}

__device__ __forceinline__ unsigned perm_b32(unsigned a, unsigned b, unsigned sel) {
#if __has_builtin(__builtin_amdgcn_perm)
  return __builtin_amdgcn_perm(a, b, sel);
#else
  union { unsigned u[2]; unsigned char c[8]; } s; s.u[0] = b; s.u[1] = a;
  unsigned r = 0;
  for (int i = 0; i < 4; ++i) r |= (unsigned)s.c[(sel >> (8*i)) & 7] << (8*i);
  return r;
#endif
}

// ---------------------------------------------------------------------------
// Wr [4096][64] f32 -> 4 int8 digit planes (w*2^36), fragment-major:
// plane p stride 256KiB; frag (kt64=k>>6, nf=e>>4) = 1KiB; within frag,
// byte ((kg*16+col)*16 + j) holds digit of k = kt64*64 + kg*16 + j, e = nf*16+col.
// Same (lane,byte)->k map as the A side, so any HW k-permutation cancels.
// ---------------------------------------------------------------------------
__global__ __launch_bounds__(256) void wr_convert(const float* __restrict__ Wr,
                                                  char* __restrict__ wl8) {
  int t = blockIdx.x * 256 + threadIdx.x;    // 16384 threads
  int e = t & 63, k16 = t >> 6;              // 16 k's per thread
  int kt64 = k16 >> 2, kgg = k16 & 3, nf = e >> 4, col = e & 15;
  int D[16];
  #pragma unroll
  for (int j = 0; j < 16; ++j)
    D[j] = digits_of(Wr[(size_t)(k16 * 16 + j) * EDIM + e] * 68719476736.0f); // 2^36
  #pragma unroll
  for (int pl = 0; pl < 4; ++pl) {
    unsigned wv[4];
    #pragma unroll
    for (int g = 0; g < 4; ++g)
      wv[g] = ((unsigned)((D[4*g+0] >> (8*pl)) & 255))
            | ((unsigned)((D[4*g+1] >> (8*pl)) & 255) << 8)
            | ((unsigned)((D[4*g+2] >> (8*pl)) & 255) << 16)
            | ((unsigned)((D[4*g+3] >> (8*pl)) & 255) << 24);
    i32x4 val = {(int)wv[0], (int)wv[1], (int)wv[2], (int)wv[3]};
    *(i32x4*)(wl8 + (size_t)pl * 262144 + (size_t)(kt64 * 4 + nf) * 1024
              + (size_t)(kgg * 16 + col) * 16) = val;
  }
}

// ---------------------------------------------------------------------------
// Fused exact router: logits via i8-MFMA fixed-point (i32 accumulation is
// EXACT; only error is input quantization ~3e-9), fp64 combine, fp64 top-8,
// sparse softmax. 512 blocks x 512 threads; 32 rows/block; 8 waves = 2Mx4N.
// ---------------------------------------------------------------------------
__global__ __launch_bounds__(512, 4) void router_fused(
    const float* __restrict__ x, const char* __restrict__ wl8,
    const float* __restrict__ br,
    float* __restrict__ out_scores, float* __restrict__ out_idx) {
  __shared__ __align__(16) char smem[2][32768];

  const int tid  = threadIdx.x;
  const int lane = tid & 63;
  const int w    = tid >> 6;
  const int mw   = w >> 2;
  const int nw   = w & 3;
  const int kg   = lane >> 4;
  const size_t row_g = (size_t)blockIdx.x * MBLK + mw * 16 + (lane & 15);
  const float* xbase = x + row_g * DDIM + kg * 16;
  const float bias = br[nw * 16 + (lane & 15)];

  i32x4 s6{}, s5{}, s4{}, s3{}, s2{};   // digit-weight classes 6..2

  auto stage = [&](int t, int b) {      // 32 KiB: 4 planes x 2 halves x 4 nf
    #pragma unroll
    for (int i = 0; i < 4; ++i) {
      int c = w * 4 + i;                // chunk = plane*8 + half*4 + nf
      int plane = c >> 3, half = (c >> 2) & 1, nf = c & 3;
      const char* src = wl8 + (size_t)plane * 262144 +
                        (size_t)((2 * t + half) * 4 + nf) * 1024 + (size_t)lane * 16;
      __builtin_amdgcn_global_load_lds(
          (const __attribute__((address_space(1))) unsigned int*)(const void*)src,
          (__attribute__((address_space(3))) unsigned int*)(void*)&smem[b][c * 1024],
          16, 0, 0);
    }
  };

  stage(0, 0);
  __syncthreads();

  for (int t = 0; t < NKT; ++t) {
    const int cb = t & 1;
    if (t + 1 < NKT) stage(t + 1, cb ^ 1);

    float4 xf[8];
    const float* p = xbase + t * 128;
    #pragma unroll
    for (int h = 0; h < 2; ++h)
      #pragma unroll
      for (int g = 0; g < 4; ++g)
        xf[h * 4 + g] = *(const float4*)(p + h * 64 + g * 4);

    const char* base = smem[cb];
    #pragma unroll
    for (int h = 0; h < 2; ++h) {
      // convert 16 x-values -> 4 digit-plane A-fragments (x * 2^25)
      i32x4 a0, a1, a2, a3;
      #pragma unroll
      for (int g = 0; g < 4; ++g) {
        float4 v = xf[h * 4 + g];
        unsigned f0 = (unsigned)digits_of(v.x * 33554432.0f);
        unsigned f1 = (unsigned)digits_of(v.y * 33554432.0f);
        unsigned f2 = (unsigned)digits_of(v.z * 33554432.0f);
        unsigned f3 = (unsigned)digits_of(v.w * 33554432.0f);
        unsigned zl01 = perm_b32(f1, f0, 0x05010400u);  // [f0_0,f1_0,f0_1,f1_1]
        unsigned zh01 = perm_b32(f1, f0, 0x07030602u);  // [f0_2,f1_2,f0_3,f1_3]
        unsigned zl23 = perm_b32(f3, f2, 0x05010400u);
        unsigned zh23 = perm_b32(f3, f2, 0x07030602u);
        a0[g] = (int)perm_b32(zl23, zl01, 0x05040100u); // plane0 bytes e0..e3
        a1[g] = (int)perm_b32(zl23, zl01, 0x07060302u);
        a2[g] = (int)perm_b32(zh23, zh01, 0x05040100u);
        a3[g] = (int)perm_b32(zh23, zh01, 0x07060302u);
      }
      i32x4 b0 = *(const i32x4*)(base + (0 * 8 + h * 4 + nw) * 1024 + lane * 16);
      i32x4 b1 = *(const i32x4*)(base + (1 * 8 + h * 4 + nw) * 1024 + lane * 16);
      i32x4 b2 = *(const i32x4*)(base + (2 * 8 + h * 4 + nw) * 1024 + lane * 16);
      i32x4 b3 = *(const i32x4*)(base + (3 * 8 + h * 4 + nw) * 1024 + lane * 16);

      s6 = __builtin_amdgcn_mfma_i32_16x16x64_i8(a3, b3, s6, 0, 0, 0);
      s5 = __builtin_amdgcn_mfma_i32_16x16x64_i8(a3, b2, s5, 0, 0, 0);
      s5 = __builtin_amdgcn_mfma_i32_16x16x64_i8(a2, b3, s5, 0, 0, 0);
      s4 = __builtin_amdgcn_mfma_i32_16x16x64_i8(a3, b1, s4, 0, 0, 0);
      s4 = __builtin_amdgcn_mfma_i32_16x16x64_i8(a2, b2, s4, 0, 0, 0);
      s4 = __builtin_amdgcn_mfma_i32_16x16x64_i8(a1, b3, s4, 0, 0, 0);
      s3 = __builtin_amdgcn_mfma_i32_16x16x64_i8(a3, b0, s3, 0, 0, 0);
      s3 = __builtin_amdgcn_mfma_i32_16x16x64_i8(a2, b1, s3, 0, 0, 0);
      s3 = __builtin_amdgcn_mfma_i32_16x16x64_i8(a1, b2, s3, 0, 0, 0);
      s3 = __builtin_amdgcn_mfma_i32_16x16x64_i8(a0, b3, s3, 0, 0, 0);
      s2 = __builtin_amdgcn_mfma_i32_16x16x64_i8(a2, b0, s2, 0, 0, 0);
      s2 = __builtin_amdgcn_mfma_i32_16x16x64_i8(a1, b1, s2, 0, 0, 0);
      s2 = __builtin_amdgcn_mfma_i32_16x16x64_i8(a0, b2, s2, 0, 0, 0);
    }
    __syncthreads();
  }

  // ---- epilogue: fp64 combine (x: 2^-25, w: 2^-36 -> class s: 2^(8s-61)) ----
  double* ls = (double*)smem;           // 32 x 64 doubles = 16 KiB
  #pragma unroll
  for (int j = 0; j < 4; ++j) {
    int r = mw * 16 + (lane >> 4) * 4 + j;   // C/D: row=(lane>>4)*4+reg
    int c = nw * 16 + (lane & 15);           //      col=lane&15
    double lg = (double)s6[j] * 0x1p-13 + (double)s5[j] * 0x1p-21
              + (double)s4[j] * 0x1p-29 + (double)s3[j] * 0x1p-37
              + (double)s2[j] * 0x1p-45 + (double)bias;
    ls[r * 64 + c] = lg;
  }
  __syncthreads();

  for (int rr = 0; rr < 4; ++rr) {
    int r = w * 4 + rr;
    double v0 = ls[r * 64 + lane];
    double cur = v0;
    bool sel  = false;
    int myidx = 0;
    double maxv = 0.0;
    #pragma unroll
    for (int k = 0; k < TOPK_K; ++k) {
      double bv = cur;
      int    bi = lane;
      #pragma unroll
      for (int off = 32; off; off >>= 1) {
        double ov = __shfl_xor(bv, off);
        int    oi = __shfl_xor(bi, off);
        if (ov > bv || (ov == bv && oi < bi)) { bv = ov; bi = oi; }
      }
      if (k == 0) maxv = bv;
      if (lane == k) myidx = bi;
      if (lane == bi) { cur = -__builtin_inf(); sel = true; }
    }
    float pv = sel ? expf((float)(v0 - maxv)) : 0.f;
    float ssum = pv;
    #pragma unroll
    for (int off = 32; off; off >>= 1) ssum += __shfl_xor(ssum, off);

    size_t rg = (size_t)blockIdx.x * MBLK + r;
    out_scores[rg * 64 + lane] = pv / ssum;
    if (lane < TOPK_K) out_idx[rg * 8 + lane] = (float)myidx;
  }
}

extern "C" void kernel_launch(void* const* d_in, const int* in_sizes, int n_in,
                              void* d_out, int out_size, void* d_ws, size_t ws_size,
                              hipStream_t stream) {
  const float* x  = (const float*)d_in[0];
  const float* Wr = (const float*)d_in[1];
  const float* br = (const float*)d_in[2];
  // d_in[3] (Wn), d_in[4] (bn): dead code in the reference — intentionally unused.

  char* wl8 = (char*)d_ws;                          // 4 planes x 256 KiB = 1 MiB
  float* out_scores = (float*)d_out;
  float* out_idx    = out_scores + (size_t)NROWS * EDIM;

  wr_convert<<<64, 256, 0, stream>>>(Wr, wl8);
  router_fused<<<NROWS / MBLK, 512, 0, stream>>>(x, wl8, br, out_scores, out_idx);
}

// Round 5
// 181.446 us; speedup vs baseline: 1.0498x; 1.0498x over previous
//
#include <hip/hip_runtime.h>
#include <math.h>

#define DDIM 4096
#define EDIM 64
#define NROWS 16384
#define MBLK 32
#define NKT 32            // K-tiles of 128
#define TOPK_K 8
#define DIGIT_BIAS 0x00808080

typedef int i32x4 __attribute__((ext_vector_type(4)));

// signed-digit int8 decomposition of v: bytes of (v+BIAS)^BIAS are signed
// digits d_p with v = sum d_p * 256^p   (exact for |v| < 2^31 - 2^23)
__device__ __forceinline__ int digits_of(float f) {
  int v = __float2int_rn(f);
  return (v + DIGIT_BIAS) ^ DIGIT_BIAS;
}

__device__ __forceinline__ unsigned perm_b32(unsigned a, unsigned b, unsigned sel) {
#if __has_builtin(__builtin_amdgcn_perm)
  return __builtin_amdgcn_perm(a, b, sel);
#else
  union { unsigned u[2]; unsigned char c[8]; } s; s.u[0] = b; s.u[1] = a;
  unsigned r = 0;
  for (int i = 0; i < 4; ++i) r |= (unsigned)s.c[(sel >> (8*i)) & 7] << (8*i);
  return r;
#endif
}

// ---------------------------------------------------------------------------
// Wr [4096][64] f32 -> 4 int8 digit planes (w*2^36), fragment-major.
// (verified in R4: idx exact)
// ---------------------------------------------------------------------------
__global__ __launch_bounds__(256) void wr_convert(const float* __restrict__ Wr,
                                                  char* __restrict__ wl8) {
  int t = blockIdx.x * 256 + threadIdx.x;    // 16384 threads
  int e = t & 63, k16 = t >> 6;              // 16 k's per thread
  int kt64 = k16 >> 2, kgg = k16 & 3, nf = e >> 4, col = e & 15;
  int D[16];
  #pragma unroll
  for (int j = 0; j < 16; ++j)
    D[j] = digits_of(Wr[(size_t)(k16 * 16 + j) * EDIM + e] * 68719476736.0f); // 2^36
  #pragma unroll
  for (int pl = 0; pl < 4; ++pl) {
    unsigned wv[4];
    #pragma unroll
    for (int g = 0; g < 4; ++g)
      wv[g] = ((unsigned)((D[4*g+0] >> (8*pl)) & 255))
            | ((unsigned)((D[4*g+1] >> (8*pl)) & 255) << 8)
            | ((unsigned)((D[4*g+2] >> (8*pl)) & 255) << 16)
            | ((unsigned)((D[4*g+3] >> (8*pl)) & 255) << 24);
    i32x4 val = {(int)wv[0], (int)wv[1], (int)wv[2], (int)wv[3]};
    *(i32x4*)(wl8 + (size_t)pl * 262144 + (size_t)(kt64 * 4 + nf) * 1024
              + (size_t)(kgg * 16 + col) * 16) = val;
  }
}

// ---------------------------------------------------------------------------
// Fused exact router: i8-MFMA fixed-point (i32 accum exact), fp64 combine,
// fp64 top-8, sparse softmax. 512 blocks x 512 threads; 32 rows/block;
// 8 waves = 2Mx4N. x register-double-buffered one K-tile ahead.
// ---------------------------------------------------------------------------
__global__ __launch_bounds__(512, 2) void router_fused(
    const float* __restrict__ x, const char* __restrict__ wl8,
    const float* __restrict__ br,
    float* __restrict__ out_scores, float* __restrict__ out_idx) {
  __shared__ __align__(16) char smem[2][32768];

  const int tid  = threadIdx.x;
  const int lane = tid & 63;
  const int w    = tid >> 6;
  const int mw   = w >> 2;
  const int nw   = w & 3;
  const int kg   = lane >> 4;
  const size_t row_g = (size_t)blockIdx.x * MBLK + mw * 16 + (lane & 15);
  const float* xbase = x + row_g * DDIM + kg * 16;
  const float bias = br[nw * 16 + (lane & 15)];

  i32x4 s6{}, s5{}, s4{}, s3{}, s2{};   // digit-weight classes 6..2

  auto stage = [&](int t, int b) {      // 32 KiB: 4 planes x 2 halves x 4 nf
    #pragma unroll
    for (int i = 0; i < 4; ++i) {
      int c = w * 4 + i;                // chunk = plane*8 + half*4 + nf
      int plane = c >> 3, half = (c >> 2) & 1, nf = c & 3;
      const char* src = wl8 + (size_t)plane * 262144 +
                        (size_t)((2 * t + half) * 4 + nf) * 1024 + (size_t)lane * 16;
      __builtin_amdgcn_global_load_lds(
          (const __attribute__((address_space(1))) unsigned int*)(const void*)src,
          (__attribute__((address_space(3))) unsigned int*)(void*)&smem[b][c * 1024],
          16, 0, 0);
    }
  };

  auto loadX = [&](int t, float4* xr) {
    const float* p = xbase + t * 128;
    #pragma unroll
    for (int h = 0; h < 2; ++h)
      #pragma unroll
      for (int g = 0; g < 4; ++g)
        xr[h * 4 + g] = *(const float4*)(p + h * 64 + g * 4);
  };

  auto compute = [&](int b, const float4* xf) {
    const char* base = smem[b];
    #pragma unroll
    for (int h = 0; h < 2; ++h) {
      // convert 16 x-values -> 4 digit-plane A-fragments (x * 2^25)
      i32x4 a0, a1, a2, a3;
      #pragma unroll
      for (int g = 0; g < 4; ++g) {
        float4 v = xf[h * 4 + g];
        unsigned f0 = (unsigned)digits_of(v.x * 33554432.0f);
        unsigned f1 = (unsigned)digits_of(v.y * 33554432.0f);
        unsigned f2 = (unsigned)digits_of(v.z * 33554432.0f);
        unsigned f3 = (unsigned)digits_of(v.w * 33554432.0f);
        unsigned zl01 = perm_b32(f1, f0, 0x05010400u);  // [f0_0,f1_0,f0_1,f1_1]
        unsigned zh01 = perm_b32(f1, f0, 0x07030602u);  // [f0_2,f1_2,f0_3,f1_3]
        unsigned zl23 = perm_b32(f3, f2, 0x05010400u);
        unsigned zh23 = perm_b32(f3, f2, 0x07030602u);
        a0[g] = (int)perm_b32(zl23, zl01, 0x05040100u); // plane0 bytes e0..e3
        a1[g] = (int)perm_b32(zl23, zl01, 0x07060302u);
        a2[g] = (int)perm_b32(zh23, zh01, 0x05040100u);
        a3[g] = (int)perm_b32(zh23, zh01, 0x07060302u);
      }
      i32x4 b0 = *(const i32x4*)(base + (0 * 8 + h * 4 + nw) * 1024 + lane * 16);
      i32x4 b1 = *(const i32x4*)(base + (1 * 8 + h * 4 + nw) * 1024 + lane * 16);
      i32x4 b2 = *(const i32x4*)(base + (2 * 8 + h * 4 + nw) * 1024 + lane * 16);
      i32x4 b3 = *(const i32x4*)(base + (3 * 8 + h * 4 + nw) * 1024 + lane * 16);

      s6 = __builtin_amdgcn_mfma_i32_16x16x64_i8(a3, b3, s6, 0, 0, 0);
      s5 = __builtin_amdgcn_mfma_i32_16x16x64_i8(a3, b2, s5, 0, 0, 0);
      s5 = __builtin_amdgcn_mfma_i32_16x16x64_i8(a2, b3, s5, 0, 0, 0);
      s4 = __builtin_amdgcn_mfma_i32_16x16x64_i8(a3, b1, s4, 0, 0, 0);
      s4 = __builtin_amdgcn_mfma_i32_16x16x64_i8(a2, b2, s4, 0, 0, 0);
      s4 = __builtin_amdgcn_mfma_i32_16x16x64_i8(a1, b3, s4, 0, 0, 0);
      s3 = __builtin_amdgcn_mfma_i32_16x16x64_i8(a3, b0, s3, 0, 0, 0);
      s3 = __builtin_amdgcn_mfma_i32_16x16x64_i8(a2, b1, s3, 0, 0, 0);
      s3 = __builtin_amdgcn_mfma_i32_16x16x64_i8(a1, b2, s3, 0, 0, 0);
      s3 = __builtin_amdgcn_mfma_i32_16x16x64_i8(a0, b3, s3, 0, 0, 0);
      s2 = __builtin_amdgcn_mfma_i32_16x16x64_i8(a2, b0, s2, 0, 0, 0);
      s2 = __builtin_amdgcn_mfma_i32_16x16x64_i8(a1, b1, s2, 0, 0, 0);
      s2 = __builtin_amdgcn_mfma_i32_16x16x64_i8(a0, b2, s2, 0, 0, 0);
    }
  };

  float4 xa0[8], xa1[8];
  stage(0, 0); loadX(0, xa0);
  __syncthreads();
  for (int t = 0; t < NKT; t += 2) {
    stage(t + 1, 1); loadX(t + 1, xa1);
    compute(0, xa0);
    __syncthreads();
    if (t + 2 < NKT) { stage(t + 2, 0); loadX(t + 2, xa0); }
    compute(1, xa1);
    __syncthreads();
  }

  // ---- epilogue: fp64 combine (x: 2^-25, w: 2^-36 -> class s: 2^(8s-61)) ----
  double* ls = (double*)smem;           // 32 x 64 doubles = 16 KiB
  #pragma unroll
  for (int j = 0; j < 4; ++j) {
    int r = mw * 16 + (lane >> 4) * 4 + j;   // C/D: row=(lane>>4)*4+reg
    int c = nw * 16 + (lane & 15);           //      col=lane&15
    double lg = (double)s6[j] * 0x1p-13 + (double)s5[j] * 0x1p-21
              + (double)s4[j] * 0x1p-29 + (double)s3[j] * 0x1p-37
              + (double)s2[j] * 0x1p-45 + (double)bias;
    ls[r * 64 + c] = lg;
  }
  __syncthreads();

  for (int rr = 0; rr < 4; ++rr) {
    int r = w * 4 + rr;
    double v0 = ls[r * 64 + lane];
    double cur = v0;
    bool sel  = false;
    int myidx = 0;
    double maxv = 0.0;
    #pragma unroll
    for (int k = 0; k < TOPK_K; ++k) {
      double bv = cur;
      int    bi = lane;
      #pragma unroll
      for (int off = 32; off; off >>= 1) {
        double ov = __shfl_xor(bv, off);
        int    oi = __shfl_xor(bi, off);
        if (ov > bv || (ov == bv && oi < bi)) { bv = ov; bi = oi; }
      }
      if (k == 0) maxv = bv;
      if (lane == k) myidx = bi;
      if (lane == bi) { cur = -__builtin_inf(); sel = true; }
    }
    float pv = sel ? expf((float)(v0 - maxv)) : 0.f;
    float ssum = pv;
    #pragma unroll
    for (int off = 32; off; off >>= 1) ssum += __shfl_xor(ssum, off);

    size_t rg = (size_t)blockIdx.x * MBLK + r;
    out_scores[rg * 64 + lane] = pv / ssum;
    if (lane < TOPK_K) out_idx[rg * 8 + lane] = (float)myidx;
  }
}

extern "C" void kernel_launch(void* const* d_in, const int* in_sizes, int n_in,
                              void* d_out, int out_size, void* d_ws, size_t ws_size,
                              hipStream_t stream) {
  const float* x  = (const float*)d_in[0];
  const float* Wr = (const float*)d_in[1];
  const float* br = (const float*)d_in[2];
  // d_in[3] (Wn), d_in[4] (bn): dead code in the reference — intentionally unused.

  char* wl8 = (char*)d_ws;                          // 4 planes x 256 KiB = 1 MiB
  float* out_scores = (float*)d_out;
  float* out_idx    = out_scores + (size_t)NROWS * EDIM;

  wr_convert<<<64, 256, 0, stream>>>(Wr, wl8);
  router_fused<<<NROWS / MBLK, 512, 0, stream>>>(x, wl8, br, out_scores, out_idx);
}

// Round 6
// 126.470 us; speedup vs baseline: 1.5061x; 1.4347x over previous
//
#include <hip/hip_runtime.h>
#include <math.h>

#define DDIM 4096
#define EDIM 64
#define NROWS 16384
#define MBLK 64
#define NKT 32            // K-tiles of 128
#define TOPK_K 8
#define DIGIT_BIAS 0x00808080

typedef int i32x4 __attribute__((ext_vector_type(4)));

// signed-digit int8 decomposition of v: bytes of (v+BIAS)^BIAS are signed
// digits d_p with v = sum d_p * 256^p   (exact for |v| < 2^31 - 2^23)
__device__ __forceinline__ int digits_of(float f) {
  int v = __float2int_rn(f);
  return (v + DIGIT_BIAS) ^ DIGIT_BIAS;
}

__device__ __forceinline__ unsigned perm_b32(unsigned a, unsigned b, unsigned sel) {
#if __has_builtin(__builtin_amdgcn_perm)
  return __builtin_amdgcn_perm(a, b, sel);
#else
  union { unsigned u[2]; unsigned char c[8]; } s; s.u[0] = b; s.u[1] = a;
  unsigned r = 0;
  for (int i = 0; i < 4; ++i) r |= (unsigned)s.c[(sel >> (8*i)) & 7] << (8*i);
  return r;
#endif
}

// ---------------------------------------------------------------------------
// Wr [4096][64] f32 -> 4 int8 digit planes (w*2^36), fragment-major.
// (verified R4/R5: idx exact)
// ---------------------------------------------------------------------------
__global__ __launch_bounds__(256) void wr_convert(const float* __restrict__ Wr,
                                                  char* __restrict__ wl8) {
  int t = blockIdx.x * 256 + threadIdx.x;    // 16384 threads
  int e = t & 63, k16 = t >> 6;              // 16 k's per thread
  int kt64 = k16 >> 2, kgg = k16 & 3, nf = e >> 4, col = e & 15;
  int D[16];
  #pragma unroll
  for (int j = 0; j < 16; ++j)
    D[j] = digits_of(Wr[(size_t)(k16 * 16 + j) * EDIM + e] * 68719476736.0f); // 2^36
  #pragma unroll
  for (int pl = 0; pl < 4; ++pl) {
    unsigned wv[4];
    #pragma unroll
    for (int g = 0; g < 4; ++g)
      wv[g] = ((unsigned)((D[4*g+0] >> (8*pl)) & 255))
            | ((unsigned)((D[4*g+1] >> (8*pl)) & 255) << 8)
            | ((unsigned)((D[4*g+2] >> (8*pl)) & 255) << 16)
            | ((unsigned)((D[4*g+3] >> (8*pl)) & 255) << 24);
    i32x4 val = {(int)wv[0], (int)wv[1], (int)wv[2], (int)wv[3]};
    *(i32x4*)(wl8 + (size_t)pl * 262144 + (size_t)(kt64 * 4 + nf) * 1024
              + (size_t)(kgg * 16 + col) * 16) = val;
  }
}

// ---------------------------------------------------------------------------
// Fused exact router. Both x (fp32, XOR-swizzled via pre-swizzled source) and
// W-digits staged through LDS with global_load_lds; m97-style 2-phase loop.
// 256 blocks x 512 threads; 64 rows/block; 8 waves = 4 mw x 2 nw (16x32 out).
// ---------------------------------------------------------------------------
__global__ __launch_bounds__(512, 2) void router_fused(
    const float* __restrict__ x, const char* __restrict__ wl8,
    const float* __restrict__ br,
    float* __restrict__ out_scores, float* __restrict__ out_idx) {
  __shared__ __align__(16) char smem[2][65536];   // per buf: [W 32K | x 32K]

  const int tid  = threadIdx.x;
  const int lane = tid & 63;
  const int w    = tid >> 6;          // 0..7
  const int mw   = w >> 1;            // 0..3  (16-row band)
  const int nw2  = w & 1;             // 0..1  (32-col band)
  const int kg   = lane >> 4;
  const int row0 = blockIdx.x * MBLK;
  const int row_l = mw * 16 + (lane & 15);
  const float bias0 = br[nw2 * 32 + (lane & 15)];
  const float bias1 = br[nw2 * 32 + 16 + (lane & 15)];

  i32x4 acc[2][5] = {};   // [nf2][class s6..s2]  (static indices after unroll)

  auto stage = [&](int t, int b) {
    // W digits: 32 KiB = 32 chunks of 1 KiB; chunk = plane*8 + half*4 + nf
    #pragma unroll
    for (int i = 0; i < 4; ++i) {
      int c = w * 4 + i;
      int plane = c >> 3, half = (c >> 2) & 1, nf = c & 3;
      const char* src = wl8 + (size_t)plane * 262144 +
                        (size_t)((2 * t + half) * 4 + nf) * 1024 + (size_t)lane * 16;
      __builtin_amdgcn_global_load_lds(
          (const __attribute__((address_space(1))) unsigned int*)(const void*)src,
          (__attribute__((address_space(3))) unsigned int*)(void*)&smem[b][c * 1024],
          16, 0, 0);
    }
    // x: 64 rows x 128 floats = 32 KiB; LDS linear, source column XOR-swizzled
    #pragma unroll
    for (int i = 0; i < 4; ++i) {
      int M = w * 256 + i * 64 + lane;        // 16B-chunk index 0..2047
      int row = M >> 5, cc = M & 31;
      const float* src = x + (size_t)(row0 + row) * DDIM + t * 128
                           + ((cc ^ (row & 7)) << 2);
      __builtin_amdgcn_global_load_lds(
          (const __attribute__((address_space(1))) unsigned int*)(const void*)src,
          (__attribute__((address_space(3))) unsigned int*)(void*)
              &smem[b][32768 + (w * 256 + i * 64) * 16],
          16, 0, 0);
    }
  };

  auto compute = [&](int b) {
    const char* Wb = smem[b];
    const char* Xb = smem[b] + 32768;
    #pragma unroll
    for (int h = 0; h < 2; ++h) {
      // lane's 16 x-values: row=row_l, k = h*64 + kg*16 + 0..15 (XOR-swizzled)
      float4 xv[4];
      #pragma unroll
      for (int c = 0; c < 4; ++c) {
        int chunk = (h * 16 + kg * 4 + c) ^ (row_l & 7);
        xv[c] = *(const float4*)(Xb + row_l * 512 + chunk * 16);
      }
      // convert -> 4 digit-plane A-fragments (x * 2^25)
      i32x4 a0, a1, a2, a3;
      #pragma unroll
      for (int g = 0; g < 4; ++g) {
        float4 v = xv[g];
        unsigned f0 = (unsigned)digits_of(v.x * 33554432.0f);
        unsigned f1 = (unsigned)digits_of(v.y * 33554432.0f);
        unsigned f2 = (unsigned)digits_of(v.z * 33554432.0f);
        unsigned f3 = (unsigned)digits_of(v.w * 33554432.0f);
        unsigned zl01 = perm_b32(f1, f0, 0x05010400u);
        unsigned zh01 = perm_b32(f1, f0, 0x07030602u);
        unsigned zl23 = perm_b32(f3, f2, 0x05010400u);
        unsigned zh23 = perm_b32(f3, f2, 0x07030602u);
        a0[g] = (int)perm_b32(zl23, zl01, 0x05040100u);
        a1[g] = (int)perm_b32(zl23, zl01, 0x07060302u);
        a2[g] = (int)perm_b32(zh23, zh01, 0x05040100u);
        a3[g] = (int)perm_b32(zh23, zh01, 0x07060302u);
      }
      #pragma unroll
      for (int nf2 = 0; nf2 < 2; ++nf2) {
        int nf = nw2 * 2 + nf2;
        i32x4 b0 = *(const i32x4*)(Wb + (0 * 8 + h * 4 + nf) * 1024 + lane * 16);
        i32x4 b1 = *(const i32x4*)(Wb + (1 * 8 + h * 4 + nf) * 1024 + lane * 16);
        i32x4 b2 = *(const i32x4*)(Wb + (2 * 8 + h * 4 + nf) * 1024 + lane * 16);
        i32x4 b3 = *(const i32x4*)(Wb + (3 * 8 + h * 4 + nf) * 1024 + lane * 16);
        acc[nf2][0] = __builtin_amdgcn_mfma_i32_16x16x64_i8(a3, b3, acc[nf2][0], 0, 0, 0);
        acc[nf2][1] = __builtin_amdgcn_mfma_i32_16x16x64_i8(a3, b2, acc[nf2][1], 0, 0, 0);
        acc[nf2][1] = __builtin_amdgcn_mfma_i32_16x16x64_i8(a2, b3, acc[nf2][1], 0, 0, 0);
        acc[nf2][2] = __builtin_amdgcn_mfma_i32_16x16x64_i8(a3, b1, acc[nf2][2], 0, 0, 0);
        acc[nf2][2] = __builtin_amdgcn_mfma_i32_16x16x64_i8(a2, b2, acc[nf2][2], 0, 0, 0);
        acc[nf2][2] = __builtin_amdgcn_mfma_i32_16x16x64_i8(a1, b3, acc[nf2][2], 0, 0, 0);
        acc[nf2][3] = __builtin_amdgcn_mfma_i32_16x16x64_i8(a3, b0, acc[nf2][3], 0, 0, 0);
        acc[nf2][3] = __builtin_amdgcn_mfma_i32_16x16x64_i8(a2, b1, acc[nf2][3], 0, 0, 0);
        acc[nf2][3] = __builtin_amdgcn_mfma_i32_16x16x64_i8(a1, b2, acc[nf2][3], 0, 0, 0);
        acc[nf2][3] = __builtin_amdgcn_mfma_i32_16x16x64_i8(a0, b3, acc[nf2][3], 0, 0, 0);
        acc[nf2][4] = __builtin_amdgcn_mfma_i32_16x16x64_i8(a2, b0, acc[nf2][4], 0, 0, 0);
        acc[nf2][4] = __builtin_amdgcn_mfma_i32_16x16x64_i8(a1, b1, acc[nf2][4], 0, 0, 0);
        acc[nf2][4] = __builtin_amdgcn_mfma_i32_16x16x64_i8(a0, b2, acc[nf2][4], 0, 0, 0);
      }
    }
  };

  stage(0, 0);
  __syncthreads();
  for (int t = 0; t < NKT; ++t) {
    if (t + 1 < NKT) stage(t + 1, (t + 1) & 1);   // issued BEFORE compute
    compute(t & 1);
    __syncthreads();                               // drain covered by compute
  }

  // ---- epilogue: fp64 combine, top-8 (exact), sparse softmax ----
  double* ls = (double*)smem;           // 64 x 64 doubles = 32 KiB
  #pragma unroll
  for (int nf2 = 0; nf2 < 2; ++nf2) {
    int cc = nw2 * 32 + nf2 * 16 + (lane & 15);
    float bs = nf2 ? bias1 : bias0;
    #pragma unroll
    for (int j = 0; j < 4; ++j) {
      int r = mw * 16 + (lane >> 4) * 4 + j;   // C/D: row=(lane>>4)*4+reg, col=lane&15
      double lg = (double)acc[nf2][0][j] * 0x1p-13 + (double)acc[nf2][1][j] * 0x1p-21
                + (double)acc[nf2][2][j] * 0x1p-29 + (double)acc[nf2][3][j] * 0x1p-37
                + (double)acc[nf2][4][j] * 0x1p-45 + (double)bs;
      ls[r * 64 + cc] = lg;
    }
  }
  __syncthreads();

  for (int rr = 0; rr < 8; ++rr) {
    int r = w * 8 + rr;
    double v0 = ls[r * 64 + lane];
    double cur = v0;
    bool sel  = false;
    int myidx = 0;
    double maxv = 0.0;
    #pragma unroll
    for (int k = 0; k < TOPK_K; ++k) {
      double bv = cur;
      int    bi = lane;
      #pragma unroll
      for (int off = 32; off; off >>= 1) {
        double ov = __shfl_xor(bv, off);
        int    oi = __shfl_xor(bi, off);
        if (ov > bv || (ov == bv && oi < bi)) { bv = ov; bi = oi; }
      }
      if (k == 0) maxv = bv;
      if (lane == k) myidx = bi;
      if (lane == bi) { cur = -__builtin_inf(); sel = true; }
    }
    float pv = sel ? expf((float)(v0 - maxv)) : 0.f;
    float ssum = pv;
    #pragma unroll
    for (int off = 32; off; off >>= 1) ssum += __shfl_xor(ssum, off);

    size_t rg = (size_t)row0 + r;
    out_scores[rg * 64 + lane] = pv / ssum;
    if (lane < TOPK_K) out_idx[rg * 8 + lane] = (float)myidx;
  }
}

extern "C" void kernel_launch(void* const* d_in, const int* in_sizes, int n_in,
                              void* d_out, int out_size, void* d_ws, size_t ws_size,
                              hipStream_t stream) {
  const float* x  = (const float*)d_in[0];
  const float* Wr = (const float*)d_in[1];
  const float* br = (const float*)d_in[2];
  // d_in[3] (Wn), d_in[4] (bn): dead code in the reference — intentionally unused.

  char* wl8 = (char*)d_ws;                          // 4 planes x 256 KiB = 1 MiB
  float* out_scores = (float*)d_out;
  float* out_idx    = out_scores + (size_t)NROWS * EDIM;

  wr_convert<<<64, 256, 0, stream>>>(Wr, wl8);
  router_fused<<<NROWS / MBLK, 512, 0, stream>>>(x, wl8, br, out_scores, out_idx);
}